// Round 1
// baseline (331.965 us; speedup 1.0000x reference)
//
#include <hip/hip_runtime.h>

// Problem geometry (fixed by the reference).
#define BATCH 64
#define IMH 512
#define IMW 512
#define NCH 3

// ---------------------------------------------------------------------------
// Kernel 1: invert the 3x3 matrix M once (double precision, rounded to f32).
// Runs as a single thread; output goes to workspace.
// ---------------------------------------------------------------------------
__global__ void invert_m_kernel(const float* __restrict__ M, float* __restrict__ Minv) {
    if (threadIdx.x != 0 || blockIdx.x != 0) return;
    double a = M[0], b = M[1], c = M[2];
    double d = M[3], e = M[4], f = M[5];
    double g = M[6], h = M[7], i = M[8];
    double A =  (e * i - f * h);
    double Bq = -(d * i - f * g);
    double Cq =  (d * h - e * g);
    double det = a * A + b * Bq + c * Cq;
    double inv_det = 1.0 / det;
    Minv[0] = (float)(A * inv_det);
    Minv[1] = (float)(-(b * i - c * h) * inv_det);
    Minv[2] = (float)((b * f - c * e) * inv_det);
    Minv[3] = (float)(Bq * inv_det);
    Minv[4] = (float)((a * i - c * g) * inv_det);
    Minv[5] = (float)(-(a * f - c * d) * inv_det);
    Minv[6] = (float)(Cq * inv_det);
    Minv[7] = (float)(-(a * h - b * g) * inv_det);
    Minv[8] = (float)((a * e - b * d) * inv_det);
}

// ---------------------------------------------------------------------------
// Kernel 2: bilinear perspective warp, one thread per output pixel (3 chans).
// dst(x, y) = bilinear_sample(src, Minv @ [x, y, 1]), BORDER_CONSTANT = 0.
// ---------------------------------------------------------------------------
__global__ __launch_bounds__(256) void warp_kernel(const float* __restrict__ img,
                                                   const float* __restrict__ Minv,
                                                   float* __restrict__ out) {
    const int idx = blockIdx.x * blockDim.x + threadIdx.x;  // 0 .. B*H*W-1
    const int x = idx & (IMW - 1);
    const int y = (idx >> 9) & (IMH - 1);
    const int b = idx >> 18;

    // Uniform across the grid; serviced from L2/L1 after first touch.
    const float m0 = Minv[0], m1 = Minv[1], m2 = Minv[2];
    const float m3 = Minv[3], m4 = Minv[4], m5 = Minv[5];
    const float m6 = Minv[6], m7 = Minv[7], m8 = Minv[8];

    const float fx = (float)x, fy = (float)y;
    const float s0 = m0 * fx + m1 * fy + m2;
    const float s1 = m3 * fx + m4 * fy + m5;
    const float s2 = m6 * fx + m7 * fy + m8;
    const float u = s0 / s2;
    const float v = s1 / s2;

    const float x0f = floorf(u);
    const float y0f = floorf(v);
    const float wx = u - x0f;
    const float wy = v - y0f;
    const int x0 = (int)x0f;
    const int y0 = (int)y0f;
    const int x1 = x0 + 1;
    const int y1 = y0 + 1;

    // Per-tap weights; zero weight where the tap is out of range
    // (identical to the reference's where(valid, val, 0) * weight).
    float w00 = (1.0f - wy) * (1.0f - wx);
    float w01 = (1.0f - wy) * wx;
    float w10 = wy * (1.0f - wx);
    float w11 = wy * wx;

    const bool vx0 = (x0 >= 0) & (x0 < IMW);
    const bool vx1 = (x1 >= 0) & (x1 < IMW);
    const bool vy0 = (y0 >= 0) & (y0 < IMH);
    const bool vy1 = (y1 >= 0) & (y1 < IMH);
    w00 = (vy0 & vx0) ? w00 : 0.0f;
    w01 = (vy0 & vx1) ? w01 : 0.0f;
    w10 = (vy1 & vx0) ? w10 : 0.0f;
    w11 = (vy1 & vx1) ? w11 : 0.0f;

    const int x0c = min(max(x0, 0), IMW - 1);
    const int x1c = min(max(x1, 0), IMW - 1);
    const int y0c = min(max(y0, 0), IMH - 1);
    const int y1c = min(max(y1, 0), IMH - 1);

    const float* base = img + (size_t)b * (IMH * IMW * NCH);
    const float* p00 = base + ((size_t)y0c * IMW + x0c) * NCH;
    const float* p01 = base + ((size_t)y0c * IMW + x1c) * NCH;
    const float* p10 = base + ((size_t)y1c * IMW + x0c) * NCH;
    const float* p11 = base + ((size_t)y1c * IMW + x1c) * NCH;

    float acc0 = w00 * p00[0] + w01 * p01[0] + w10 * p10[0] + w11 * p11[0];
    float acc1 = w00 * p00[1] + w01 * p01[1] + w10 * p10[1] + w11 * p11[1];
    float acc2 = w00 * p00[2] + w01 * p01[2] + w10 * p10[2] + w11 * p11[2];

    float* o = out + (size_t)idx * NCH;
    o[0] = acc0;
    o[1] = acc1;
    o[2] = acc2;
}

extern "C" void kernel_launch(void* const* d_in, const int* in_sizes, int n_in,
                              void* d_out, int out_size, void* d_ws, size_t ws_size,
                              hipStream_t stream) {
    const float* imgs = (const float*)d_in[0];
    const float* M = (const float*)d_in[1];
    float* out = (float*)d_out;
    float* minv = (float*)d_ws;  // 9 floats of scratch

    invert_m_kernel<<<1, 64, 0, stream>>>(M, minv);

    const int total = BATCH * IMH * IMW;  // threads = pixels
    warp_kernel<<<total / 256, 256, 0, stream>>>(imgs, minv, out);
}